// Round 1
// baseline (5420.906 us; speedup 1.0000x reference)
//
#include <hip/hip_runtime.h>
#include <hip/hip_bf16.h>
#include <cstdint>
#include <cstddef>

// ---------------------------------------------------------------------------
// RANNet: 2-layer recurrent additive network, B=128 S=2048 D=H=256, fc head.
// Round 3: remove the per-step vmcnt(0) barrier drain in the recurrence.
//  - __syncthreads() drained the global preact prefetch (HBM ~900cy) every
//    step. Replaced with raw "s_waitcnt lgkmcnt(0); s_barrier" (LDS-visibility
//    only) so global loads stay in flight across the barrier (T4 technique).
//  - Prefetch deepened to 2 steps: 4 statically-named register buffers,
//    main loop unrolled x4 (T is a power of two >= 32).
// ---------------------------------------------------------------------------

typedef __bf16 bf16;
typedef __bf16 bf16x8 __attribute__((ext_vector_type(8)));
typedef __bf16 bf16x4 __attribute__((ext_vector_type(4)));
typedef float  floatx4 __attribute__((ext_vector_type(4)));

#define B_   128
#define S_   2048
#define H_   256
#define NEG_LOG2E -1.442695040888963f

// ---------------------------------------------------------------------------
// Weight prep: concat + fp32->bf16 ( W*cat rows = [Wf;Wi;Wx], U*cat = [Uf;Ui] )
// fcWT = transpose(fcW) kept fp32 for the epilogue.
// ---------------------------------------------------------------------------
__global__ void prep_weights(
    const float* __restrict__ Wf0, const float* __restrict__ Wi0, const float* __restrict__ Wx0,
    const float* __restrict__ Wf1, const float* __restrict__ Wi1, const float* __restrict__ Wx1,
    const float* __restrict__ Uf0, const float* __restrict__ Ui0,
    const float* __restrict__ Uf1, const float* __restrict__ Ui1,
    const float* __restrict__ bf0, const float* __restrict__ bi0, const float* __restrict__ bx0,
    const float* __restrict__ bf1, const float* __restrict__ bi1, const float* __restrict__ bx1,
    const float* __restrict__ fcW,
    bf16* __restrict__ W0cat, bf16* __restrict__ W1cat,
    bf16* __restrict__ U0cat, bf16* __restrict__ U1cat,
    float* __restrict__ b0cat, float* __restrict__ b1cat, float* __restrict__ fcWT)
{
    int tid = blockIdx.x * blockDim.x + threadIdx.x;
    int nth = gridDim.x * blockDim.x;
    for (int idx = tid; idx < 768 * 256; idx += nth) {
        int r = idx >> 8, k = idx & 255, rr = r & 255;
        const float* s0 = (r < 256) ? Wf0 : ((r < 512) ? Wi0 : Wx0);
        const float* s1 = (r < 256) ? Wf1 : ((r < 512) ? Wi1 : Wx1);
        W0cat[idx] = (bf16)s0[rr * 256 + k];
        W1cat[idx] = (bf16)s1[rr * 256 + k];
    }
    for (int idx = tid; idx < 512 * 256; idx += nth) {
        int r = idx >> 8, k = idx & 255, rr = r & 255;
        U0cat[idx] = (bf16)((r < 256 ? Uf0 : Ui0)[rr * 256 + k]);
        U1cat[idx] = (bf16)((r < 256 ? Uf1 : Ui1)[rr * 256 + k]);
    }
    for (int idx = tid; idx < 768; idx += nth) {
        const float* s0 = (idx < 256) ? bf0 : ((idx < 512) ? bi0 : bx0);
        const float* s1 = (idx < 256) ? bf1 : ((idx < 512) ? bi1 : bx1);
        b0cat[idx] = s0[idx & 255];
        b1cat[idx] = s1[idx & 255];
    }
    for (int idx = tid; idx < 256 * 256; idx += nth) {
        int h = idx >> 8, o = idx & 255;
        fcWT[idx] = fcW[o * 256 + h];   // fcWT[h][o]
    }
}

// ---------------------------------------------------------------------------
// x (fp32, [B][S][D]) chunk -> xa (bf16, [T][B][D], t chunk-local)
// ---------------------------------------------------------------------------
__global__ void convert_x(const float* __restrict__ x, bf16* __restrict__ xa, int t0, int T)
{
    int tid = blockIdx.x * blockDim.x + threadIdx.x;   // T*128*64 threads
    int d4 = tid & 63;
    int b  = (tid >> 6) & 127;
    int t  = tid >> 13;
    if (t >= T) return;
    const float4* src = (const float4*)(x + ((size_t)b * S_ + t0 + t) * H_) + d4;
    float4 v = *src;
    bf16x4 o = { (bf16)v.x, (bf16)v.y, (bf16)v.z, (bf16)v.w };
    *((bf16x4*)(xa + ((size_t)t * B_ + b) * H_) + d4) = o;
}

// ---------------------------------------------------------------------------
// Pre-activation GEMM: C[M][768] = A[M][256] @ Wcat[768][256]^T + bias,
// written f32 into rec-fragment order:
//   preP float offset = t*98304 + ((wg*8+wv)*6 + g*2+nt)*256 + qk*64 + qm*4 (+r)
// where t = chunk-local timestep (= blockIdx.x here since 128 rows == one t),
// b = m&127, wg=b>>4, qk=(b>>2)&3, r=b&3; c = gate col: g=c>>8, ch=c&255,
// wv=ch>>5, nt=(ch>>4)&1, qm=ch&15.  f/i (g<2) pre-scaled by -log2(e).
// ---------------------------------------------------------------------------
__global__ __launch_bounds__(256) void gemm_preact(
    const bf16* __restrict__ A, const bf16* __restrict__ W,
    const float* __restrict__ bias, float* __restrict__ preP)
{
    __shared__ bf16 At[128 * 32];   // [row][k] 64B rows
    __shared__ bf16 Bt[128 * 32];
    int m0 = blockIdx.x * 128;
    int n0 = blockIdx.y * 128;
    int tid = threadIdx.x;
    int lane = tid & 63, wave = tid >> 6;
    int wm = (wave >> 1) * 64, wn = (wave & 1) * 64;
    int qm = lane & 15, qk = lane >> 4;
    floatx4 acc[4][4] = {};

    for (int k0 = 0; k0 < 256; k0 += 32) {
#pragma unroll
        for (int j = 0; j < 2; ++j) {
            int c = tid * 2 + j;            // 16B chunk id
            int row = c >> 2, kc = c & 3;
            *(bf16x8*)(At + c * 8) = *(const bf16x8*)(A + (size_t)(m0 + row) * 256 + k0 + kc * 8);
            *(bf16x8*)(Bt + c * 8) = *(const bf16x8*)(W + (size_t)(n0 + row) * 256 + k0 + kc * 8);
        }
        __syncthreads();
        bf16x8 af[4], bfr[4];
#pragma unroll
        for (int i = 0; i < 4; ++i) {
            af[i]  = *(const bf16x8*)(At + (wm + i * 16 + qm) * 32 + qk * 8);
            bfr[i] = *(const bf16x8*)(Bt + (wn + i * 16 + qm) * 32 + qk * 8);
        }
#pragma unroll
        for (int mi = 0; mi < 4; ++mi)
#pragma unroll
            for (int ni = 0; ni < 4; ++ni)
                acc[mi][ni] = __builtin_amdgcn_mfma_f32_16x16x32_bf16(af[mi], bfr[ni], acc[mi][ni], 0, 0, 0);
        __syncthreads();
    }
    // epilogue: scatter 16B stores into rec-fragment layout
    int t = blockIdx.x;                       // 128 rows == exactly one timestep
#pragma unroll
    for (int mi = 0; mi < 4; ++mi) {
        int b = wm + mi * 16 + qk * 4;        // + r
        int wg = b >> 4;
#pragma unroll
        for (int ni = 0; ni < 4; ++ni) {
            int c = n0 + wn + ni * 16 + qm;
            int g = c >> 8, ch = c & 255, wv = ch >> 5, nt = (ch >> 4) & 1;
            float bb = bias[c];
            float4 v;
            float* vp = (float*)&v;
#pragma unroll
            for (int r = 0; r < 4; ++r) {
                float val = acc[mi][ni][r] + bb;
                vp[r] = (g < 2) ? NEG_LOG2E * val : val;
            }
            size_t off = (size_t)t * 98304 + (size_t)((wg * 8 + wv) * 6 + g * 2 + nt) * 256
                       + qk * 64 + qm * 4;
            *(float4*)(preP + off) = v;
        }
    }
}

// ---------------------------------------------------------------------------
// Recurrence: 8 WGs x 16 batch, 512 thr (8 waves). Wave w owns h-cols
// [32w, 32w+32) and computes BOTH f and i gates for them (no exchange).
// U kept as stationary register B-fragments (Uf+Ui = 128 regs/lane, AGPR-able).
// h: fp32 master in regs; bf16 copy in double-buffered LDS for A-fragments.
// ONE raw barrier per step (lgkmcnt-only: LDS visibility, global loads stay
// in flight across it). Depth-2 software prefetch of preacts (4 reg buffers).
// ---------------------------------------------------------------------------
__global__ __launch_bounds__(512) void rec_layer(
    const float* __restrict__ preP,  // [T][8wg][8wv][6 chunks][256 floats]
    bf16* __restrict__ hout,         // [T][128][256] bf16, or nullptr
    const bf16* __restrict__ Ucat,   // [512][256] = [Uf;Ui]
    float* __restrict__ hstate,      // [128][256] in/out
    int T)
{
    __shared__ bf16 hb[2][16 * 264];     // [buf][b][256+8pad]
    const int tid = threadIdx.x, lane = tid & 63, wave = tid >> 6;
    const int qm = lane & 15, qk = lane >> 4;
    const int wg = blockIdx.x, bbase = wg * 16, cb = wave * 32;

    // stationary U fragments (B-operand layout): row n = col index, k contig
    bf16x8 Ufr[2][8], Uir[2][8];
#pragma unroll
    for (int nt = 0; nt < 2; ++nt)
#pragma unroll
        for (int kt = 0; kt < 8; ++kt) {
            Ufr[nt][kt] = *(const bf16x8*)(Ucat + (size_t)(cb + nt * 16 + qm) * 256 + kt * 32 + qk * 8);
            Uir[nt][kt] = *(const bf16x8*)(Ucat + (size_t)(256 + cb + nt * 16 + qm) * 256 + kt * 32 + qk * 8);
        }
    {   // init LDS h (buf 0) from fp32 state
        int row = tid >> 5, c8 = (tid & 31) * 8;
        const float* hs = hstate + (size_t)(bbase + row) * 256 + c8;
        bf16x8 v;
#pragma unroll
        for (int j = 0; j < 8; ++j) v[j] = (bf16)hs[j];
        *(bf16x8*)(hb[0] + row * 264 + c8) = v;
    }
    float hm[2][4];   // fp32 master: (b = qk*4+r, c = cb+nt*16+qm)
#pragma unroll
    for (int nt = 0; nt < 2; ++nt)
#pragma unroll
        for (int r = 0; r < 4; ++r)
            hm[nt][r] = hstate[(size_t)(bbase + qk * 4 + r) * 256 + cb + nt * 16 + qm];
    __syncthreads();

    const float4* pw = (const float4*)preP + (size_t)(wg * 8 + wave) * 384 + lane;
#define PLD(dst, tt) { size_t o_ = (size_t)(tt) * 24576;                        \
        dst[0] = pw[o_];       dst[1] = pw[o_ + 64];  dst[2] = pw[o_ + 128];    \
        dst[3] = pw[o_ + 192]; dst[4] = pw[o_ + 256]; dst[5] = pw[o_ + 320]; }

    int cur = 0;

    auto step = [&](int t, const float4* p) {
        floatx4 accf[2] = {}, acci[2] = {};
        const bf16* hc = hb[cur];
#pragma unroll
        for (int kt = 0; kt < 8; ++kt) {
            bf16x8 a = *(const bf16x8*)(hc + qm * 264 + kt * 32 + qk * 8);
            accf[0] = __builtin_amdgcn_mfma_f32_16x16x32_bf16(a, Ufr[0][kt], accf[0], 0, 0, 0);
            accf[1] = __builtin_amdgcn_mfma_f32_16x16x32_bf16(a, Ufr[1][kt], accf[1], 0, 0, 0);
            acci[0] = __builtin_amdgcn_mfma_f32_16x16x32_bf16(a, Uir[0][kt], acci[0], 0, 0, 0);
            acci[1] = __builtin_amdgcn_mfma_f32_16x16x32_bf16(a, Uir[1][kt], acci[1], 0, 0, 0);
        }
        bf16* hn = hb[cur ^ 1];
#pragma unroll
        for (int nt = 0; nt < 2; ++nt)
#pragma unroll
            for (int r = 0; r < 4; ++r) {
                float pf = ((const float*)&p[nt])[r];        // chunk g*2+nt
                float pi = ((const float*)&p[2 + nt])[r];
                float px = ((const float*)&p[4 + nt])[r];
                // f = sigmoid(accf+xf) ; i = sigmoid(acci+xi); h = f*h + i*xp
                // = [h*(1+ei) + xp*(1+ef)] / [(1+ef)(1+ei)],  e* = exp2(-K*z)
                float ef = fminf(fmaf(accf[nt][r], NEG_LOG2E, pf), 80.0f);
                float ei = fminf(fmaf(acci[nt][r], NEG_LOG2E, pi), 80.0f);
                float A1 = 1.0f + __builtin_amdgcn_exp2f(ef);
                float B1 = 1.0f + __builtin_amdgcn_exp2f(ei);
                float N  = fmaf(hm[nt][r], B1, px * A1);
                float h  = N * __builtin_amdgcn_rcpf(A1 * B1);
                hm[nt][r] = h;
                hn[(qk * 4 + r) * 264 + cb + nt * 16 + qm] = (bf16)h;
            }
        // LDS-visibility barrier ONLY: do NOT drain vmcnt — the global
        // preact prefetch loads stay in flight across the barrier (T4).
        asm volatile("s_waitcnt lgkmcnt(0)\n\ts_barrier" ::: "memory");
        if (hout) {   // coalesced store of h_t from the just-written buffer
            int row = tid >> 5, c8 = (tid & 31) * 8;
            bf16x8 v = *(const bf16x8*)(hn + row * 264 + c8);
            *(bf16x8*)(hout + ((size_t)t * 128 + bbase + row) * 256 + c8) = v;
        }
        cur ^= 1;
    };

    // depth-2 prefetch, 4 statically-named buffers, loop unrolled x4
    // (T is a power of two >= 32, so T % 4 == 0)
    float4 bA[6], bB[6], bC[6], bD[6];
    PLD(bA, 0);
    PLD(bB, 1);
    for (int t = 0; t < T; t += 4) {
        PLD(bC, (t + 2 < T) ? t + 2 : T - 1);
        step(t, bA);
        PLD(bD, (t + 3 < T) ? t + 3 : T - 1);
        step(t + 1, bB);
        PLD(bA, (t + 4 < T) ? t + 4 : T - 1);
        step(t + 2, bC);
        PLD(bB, (t + 5 < T) ? t + 5 : T - 1);
        step(t + 3, bD);
    }
#undef PLD
#pragma unroll
    for (int nt = 0; nt < 2; ++nt)
#pragma unroll
        for (int r = 0; r < 4; ++r)
            hstate[(size_t)(bbase + qk * 4 + r) * 256 + cb + nt * 16 + qm] = hm[nt][r];
}

// ---------------------------------------------------------------------------
// fc head: out[b][o] = fcb[o] + sum_h h2[b][h] * fcWT[h][o]   (all fp32)
// ---------------------------------------------------------------------------
__global__ void fc_head(const float* __restrict__ h2, const float* __restrict__ fcWT,
                        const float* __restrict__ fcb, float* __restrict__ out)
{
    int b = blockIdx.x, o = threadIdx.x;
    __shared__ float hrow[256];
    hrow[o] = h2[(size_t)b * 256 + o];
    __syncthreads();
    float acc = fcb[o];
#pragma unroll 8
    for (int h = 0; h < 256; ++h)
        acc = fmaf(hrow[h], fcWT[h * 256 + o], acc);
    out[(size_t)b * 256 + o] = acc;
}

// ---------------------------------------------------------------------------
extern "C" void kernel_launch(void* const* d_in, const int* in_sizes, int n_in,
                              void* d_out, int out_size, void* d_ws, size_t ws_size,
                              hipStream_t stream)
{
    (void)in_sizes; (void)n_in; (void)out_size;
    const float* x   = (const float*)d_in[0];
    const float* Wf0 = (const float*)d_in[1];
    const float* bf0 = (const float*)d_in[2];
    const float* Uf0 = (const float*)d_in[3];
    const float* Wi0 = (const float*)d_in[4];
    const float* bi0 = (const float*)d_in[5];
    const float* Ui0 = (const float*)d_in[6];
    const float* Wx0 = (const float*)d_in[7];
    const float* bx0 = (const float*)d_in[8];
    const float* Wf1 = (const float*)d_in[9];
    const float* bf1 = (const float*)d_in[10];
    const float* Uf1 = (const float*)d_in[11];
    const float* Wi1 = (const float*)d_in[12];
    const float* bi1 = (const float*)d_in[13];
    const float* Ui1 = (const float*)d_in[14];
    const float* Wx1 = (const float*)d_in[15];
    const float* bx1 = (const float*)d_in[16];
    const float* fcW = (const float*)d_in[17];
    const float* fcb = (const float*)d_in[18];

    char* p = (char*)d_ws;
    auto alloc = [&](size_t bytes) -> char* {
        char* r = p; p += (bytes + 255) & ~(size_t)255; return r;
    };
    bf16*  W0cat = (bf16*)alloc(768 * 256 * 2);
    bf16*  W1cat = (bf16*)alloc(768 * 256 * 2);
    bf16*  U0cat = (bf16*)alloc(512 * 256 * 2);
    bf16*  U1cat = (bf16*)alloc(512 * 256 * 2);
    float* b0cat = (float*)alloc(768 * 4);
    float* b1cat = (float*)alloc(768 * 4);
    float* fcWT  = (float*)alloc(256 * 256 * 4);
    float* h0s   = (float*)alloc(128 * 256 * 4);
    float* h1s   = (float*)alloc(128 * 256 * 4);
    size_t fixed = (size_t)(p - (char*)d_ws);

    // per-chunk bytes = T_c * (128*256*2 + 128*768*4 + 128*256*2 + 128*768*4)
    //                 = T_c * 917504
    int T_c = 2048;
    while (T_c > 32 && fixed + (size_t)T_c * 917504 + 4096 > ws_size) T_c >>= 1;
    bf16*  xa   = (bf16*)alloc((size_t)T_c * 128 * 256 * 2);
    float* pre0 = (float*)alloc((size_t)T_c * 128 * 768 * 4);
    bf16*  h1b  = (bf16*)alloc((size_t)T_c * 128 * 256 * 2);
    float* pre1 = (float*)alloc((size_t)T_c * 128 * 768 * 4);

    hipMemsetAsync(h0s, 0, 128 * 256 * 4, stream);
    hipMemsetAsync(h1s, 0, 128 * 256 * 4, stream);

    prep_weights<<<512, 256, 0, stream>>>(Wf0, Wi0, Wx0, Wf1, Wi1, Wx1,
                                          Uf0, Ui0, Uf1, Ui1,
                                          bf0, bi0, bx0, bf1, bi1, bx1, fcW,
                                          W0cat, W1cat, U0cat, U1cat, b0cat, b1cat, fcWT);

    int NC = S_ / T_c;
    for (int c = 0; c < NC; ++c) {
        int t0 = c * T_c;
        convert_x<<<T_c * 32, 256, 0, stream>>>(x, xa, t0, T_c);
        gemm_preact<<<dim3(T_c, 6), 256, 0, stream>>>(xa, W0cat, b0cat, pre0);
        rec_layer<<<8, 512, 0, stream>>>(pre0, h1b, U0cat, h0s, T_c);
        gemm_preact<<<dim3(T_c, 6), 256, 0, stream>>>(h1b, W1cat, b1cat, pre1);
        rec_layer<<<8, 512, 0, stream>>>(pre1, nullptr, U1cat, h1s, T_c);
    }
    fc_head<<<128, 256, 0, stream>>>(h1s, fcWT, fcb, (float*)d_out);
}

// Round 3
// 4213.865 us; speedup vs baseline: 1.2864x; 1.2864x over previous
//
#include <hip/hip_runtime.h>
#include <hip/hip_bf16.h>
#include <cstdint>
#include <cstddef>

// ---------------------------------------------------------------------------
// RANNet: 2-layer recurrent additive network, B=128 S=2048 D=H=256, fc head.
// Round 5: scale the recurrence to 32 CUs (re-land of round 4, permlane-free).
//  - rec_layer: 32 WGs x 4 batch rows (was 8 x 16). Batch rows are the only
//    independent axis; cols can't split (U.h reduction). M=16 MFMA with A
//    rows read as (qm&3) -> A rows replicate mod 4 -> C rows replicate mod 4:
//    EVERY lane holds all 4 valid rows z[j][col=lane&15] in its 4 acc regs.
//    Ownership (row=lane>>4, col=lane&15) is a pure per-lane register select
//    (3 v_cndmask, masks hoisted) -- no cross-lane ops at all.
//  - Per-lane epilogue work drops 4x (2 h-elements/lane, 6 transcendentals).
//  - preP re-blocked [t][wg32][c768][4rows]: GEMM keeps coalesced float4
//    stores; rec does 6 coalesced dword loads/lane/step, depth-2 prefetch.
//  - LDS h tile stride 544B; lgkm-only barrier per step (vm stays in flight).
// ---------------------------------------------------------------------------

typedef __bf16 bf16;
typedef __bf16 bf16x8 __attribute__((ext_vector_type(8)));
typedef __bf16 bf16x4 __attribute__((ext_vector_type(4)));
typedef __bf16 bf16x2 __attribute__((ext_vector_type(2)));
typedef float  floatx4 __attribute__((ext_vector_type(4)));

#define B_   128
#define S_   2048
#define H_   256
#define NEG_LOG2E -1.442695040888963f

// ---------------------------------------------------------------------------
// Weight prep: concat + fp32->bf16 ( W*cat rows = [Wf;Wi;Wx], U*cat = [Uf;Ui] )
// fcWT = transpose(fcW) kept fp32 for the epilogue.
// ---------------------------------------------------------------------------
__global__ void prep_weights(
    const float* __restrict__ Wf0, const float* __restrict__ Wi0, const float* __restrict__ Wx0,
    const float* __restrict__ Wf1, const float* __restrict__ Wi1, const float* __restrict__ Wx1,
    const float* __restrict__ Uf0, const float* __restrict__ Ui0,
    const float* __restrict__ Uf1, const float* __restrict__ Ui1,
    const float* __restrict__ bf0, const float* __restrict__ bi0, const float* __restrict__ bx0,
    const float* __restrict__ bf1, const float* __restrict__ bi1, const float* __restrict__ bx1,
    const float* __restrict__ fcW,
    bf16* __restrict__ W0cat, bf16* __restrict__ W1cat,
    bf16* __restrict__ U0cat, bf16* __restrict__ U1cat,
    float* __restrict__ b0cat, float* __restrict__ b1cat, float* __restrict__ fcWT)
{
    int tid = blockIdx.x * blockDim.x + threadIdx.x;
    int nth = gridDim.x * blockDim.x;
    for (int idx = tid; idx < 768 * 256; idx += nth) {
        int r = idx >> 8, k = idx & 255, rr = r & 255;
        const float* s0 = (r < 256) ? Wf0 : ((r < 512) ? Wi0 : Wx0);
        const float* s1 = (r < 256) ? Wf1 : ((r < 512) ? Wi1 : Wx1);
        W0cat[idx] = (bf16)s0[rr * 256 + k];
        W1cat[idx] = (bf16)s1[rr * 256 + k];
    }
    for (int idx = tid; idx < 512 * 256; idx += nth) {
        int r = idx >> 8, k = idx & 255, rr = r & 255;
        U0cat[idx] = (bf16)((r < 256 ? Uf0 : Ui0)[rr * 256 + k]);
        U1cat[idx] = (bf16)((r < 256 ? Uf1 : Ui1)[rr * 256 + k]);
    }
    for (int idx = tid; idx < 768; idx += nth) {
        const float* s0 = (idx < 256) ? bf0 : ((idx < 512) ? bi0 : bx0);
        const float* s1 = (idx < 256) ? bf1 : ((idx < 512) ? bi1 : bx1);
        b0cat[idx] = s0[idx & 255];
        b1cat[idx] = s1[idx & 255];
    }
    for (int idx = tid; idx < 256 * 256; idx += nth) {
        int h = idx >> 8, o = idx & 255;
        fcWT[idx] = fcW[o * 256 + h];   // fcWT[h][o]
    }
}

// ---------------------------------------------------------------------------
// x (fp32, [B][S][D]) chunk -> xa (bf16, [T][B][D], t chunk-local)
// ---------------------------------------------------------------------------
__global__ void convert_x(const float* __restrict__ x, bf16* __restrict__ xa, int t0, int T)
{
    int tid = blockIdx.x * blockDim.x + threadIdx.x;   // T*128*64 threads
    int d4 = tid & 63;
    int b  = (tid >> 6) & 127;
    int t  = tid >> 13;
    if (t >= T) return;
    const float4* src = (const float4*)(x + ((size_t)b * S_ + t0 + t) * H_) + d4;
    float4 v = *src;
    bf16x4 o = { (bf16)v.x, (bf16)v.y, (bf16)v.z, (bf16)v.w };
    *((bf16x4*)(xa + ((size_t)t * B_ + b) * H_) + d4) = o;
}

// ---------------------------------------------------------------------------
// Pre-activation GEMM: C[M][768] = A[M][256] @ Wcat[768][256]^T + bias.
// Output layout (f32): preP[(t*32 + wg)*3072 + c*4 + r]
//   t = blockIdx.x (128 rows == one timestep), wg = (m&127)>>2, r = m&3,
//   c = gate col 0..767.  f/i (c<512) pre-scaled by -log2(e).
// Stores remain coalesced float4 (r=0..3 contiguous).
// ---------------------------------------------------------------------------
__global__ __launch_bounds__(256) void gemm_preact(
    const bf16* __restrict__ A, const bf16* __restrict__ W,
    const float* __restrict__ bias, float* __restrict__ preP)
{
    __shared__ bf16 At[128 * 32];   // [row][k] 64B rows
    __shared__ bf16 Bt[128 * 32];
    int m0 = blockIdx.x * 128;
    int n0 = blockIdx.y * 128;
    int tid = threadIdx.x;
    int lane = tid & 63, wave = tid >> 6;
    int wm = (wave >> 1) * 64, wn = (wave & 1) * 64;
    int qm = lane & 15, qk = lane >> 4;
    floatx4 acc[4][4] = {};

    for (int k0 = 0; k0 < 256; k0 += 32) {
#pragma unroll
        for (int j = 0; j < 2; ++j) {
            int c = tid * 2 + j;            // 16B chunk id
            int row = c >> 2, kc = c & 3;
            *(bf16x8*)(At + c * 8) = *(const bf16x8*)(A + (size_t)(m0 + row) * 256 + k0 + kc * 8);
            *(bf16x8*)(Bt + c * 8) = *(const bf16x8*)(W + (size_t)(n0 + row) * 256 + k0 + kc * 8);
        }
        __syncthreads();
        bf16x8 af[4], bfr[4];
#pragma unroll
        for (int i = 0; i < 4; ++i) {
            af[i]  = *(const bf16x8*)(At + (wm + i * 16 + qm) * 32 + qk * 8);
            bfr[i] = *(const bf16x8*)(Bt + (wn + i * 16 + qm) * 32 + qk * 8);
        }
#pragma unroll
        for (int mi = 0; mi < 4; ++mi)
#pragma unroll
            for (int ni = 0; ni < 4; ++ni)
                acc[mi][ni] = __builtin_amdgcn_mfma_f32_16x16x32_bf16(af[mi], bfr[ni], acc[mi][ni], 0, 0, 0);
        __syncthreads();
    }
    int t = blockIdx.x;
#pragma unroll
    for (int mi = 0; mi < 4; ++mi) {
        int b = wm + mi * 16 + qk * 4;        // + r ; multiple of 4
        int wgi = b >> 2;
#pragma unroll
        for (int ni = 0; ni < 4; ++ni) {
            int c = n0 + wn + ni * 16 + qm;
            int g = c >> 8;
            float bb = bias[c];
            float4 v;
            float* vp = (float*)&v;
#pragma unroll
            for (int r = 0; r < 4; ++r) {
                float val = acc[mi][ni][r] + bb;
                vp[r] = (g < 2) ? NEG_LOG2E * val : val;
            }
            *(float4*)(preP + ((size_t)t * 32 + wgi) * 3072 + (size_t)c * 4) = v;
        }
    }
}

// ---------------------------------------------------------------------------
// Recurrence: 32 WGs x 4 batch rows, 512 thr (8 waves). Wave w owns h-cols
// [32w, 32w+32) and computes BOTH f and i gates (no exchange). M=16 MFMA,
// A rows read as (qm&3) -> C rows replicate mod 4, so every lane's 4 acc
// regs hold z[0..3][col=lane&15]; ownership (row=lane>>4, col=lane&15) is a
// per-lane 4->1 register select. One lgkm-only barrier per step; depth-2
// prefetch of 6 dwords/lane/step.
// ---------------------------------------------------------------------------
__global__ __launch_bounds__(512) void rec_layer(
    const float* __restrict__ preP,  // [T][32 wg][768 c][4 r] f32
    bf16* __restrict__ hout,         // [T][128][256] bf16, or nullptr
    const bf16* __restrict__ Ucat,   // [512][256] = [Uf;Ui]
    float* __restrict__ hstate,      // [128][256] in/out
    int T)
{
    __shared__ bf16 hb[2][4 * 272];      // [buf][row][256+16 pad] : 544B row stride
    const int tid = threadIdx.x, lane = tid & 63, wave = tid >> 6;
    const int qm = lane & 15, qk = lane >> 4;
    const int row = qk;                  // 0..3 = output row this lane owns
    const int colq = qm;                 // 0..15
    const int wg = blockIdx.x, bbase = wg * 4, cb = wave * 32;
    const bool selhi16 = (lane & 16) != 0;   // reg-select masks (hoisted)
    const bool selhi32 = (lane & 32) != 0;

    // stationary U fragments (B-operand layout): row n = col index, k contig
    bf16x8 Ufr[2][8], Uir[2][8];
#pragma unroll
    for (int nt = 0; nt < 2; ++nt)
#pragma unroll
        for (int kt = 0; kt < 8; ++kt) {
            Ufr[nt][kt] = *(const bf16x8*)(Ucat + (size_t)(cb + nt * 16 + qm) * 256 + kt * 32 + qk * 8);
            Uir[nt][kt] = *(const bf16x8*)(Ucat + (size_t)(256 + cb + nt * 16 + qm) * 256 + kt * 32 + qk * 8);
        }
    {   // init LDS h (buf 0) from fp32 state: 4 rows x 256 cols, 2 cols/thread
        int r2 = tid >> 7, c2 = (tid & 127) * 2;
        const float* hs = hstate + (size_t)(bbase + r2) * 256 + c2;
        bf16x2 v = { (bf16)hs[0], (bf16)hs[1] };
        *(bf16x2*)(hb[0] + r2 * 272 + c2) = v;
    }
    float hm0 = hstate[(size_t)(bbase + row) * 256 + cb + colq];
    float hm1 = hstate[(size_t)(bbase + row) * 256 + cb + 16 + colq];
    __syncthreads();

    // per-lane preact base: idx = t*98304 + wg*3072 + (g*256+cb+nt*16+colq)*4 + row
    const float* pw = preP + (size_t)wg * 3072 + (size_t)((cb + colq) * 4 + row);
#define PLD(dst, tt) { size_t o_ = (size_t)(tt) * 98304;                          \
        dst[0] = pw[o_];        dst[1] = pw[o_ + 64];   dst[2] = pw[o_ + 1024];   \
        dst[3] = pw[o_ + 1088]; dst[4] = pw[o_ + 2048]; dst[5] = pw[o_ + 2112]; }

    int cur = 0;

    // every lane: reg j = z[row=j][col=lane&15]  ->  pick reg (lane>>4)
    auto spread = [&](floatx4 v) -> float {
        float s01 = selhi16 ? v[1] : v[0];
        float s23 = selhi16 ? v[3] : v[2];
        return selhi32 ? s23 : s01;
    };

    auto step = [&](int t, const float* p) {
        floatx4 f0{}, f1{}, i0{}, i1{};
        const bf16* hc = hb[cur];
#pragma unroll
        for (int kt = 0; kt < 8; ++kt) {
            bf16x8 a = *(const bf16x8*)(hc + (qm & 3) * 272 + kt * 32 + qk * 8);
            f0 = __builtin_amdgcn_mfma_f32_16x16x32_bf16(a, Ufr[0][kt], f0, 0, 0, 0);
            f1 = __builtin_amdgcn_mfma_f32_16x16x32_bf16(a, Ufr[1][kt], f1, 0, 0, 0);
            i0 = __builtin_amdgcn_mfma_f32_16x16x32_bf16(a, Uir[0][kt], i0, 0, 0, 0);
            i1 = __builtin_amdgcn_mfma_f32_16x16x32_bf16(a, Uir[1][kt], i1, 0, 0, 0);
        }
        float zf0 = spread(f0), zf1 = spread(f1);
        float zi0 = spread(i0), zi1 = spread(i1);
        bf16* hn = hb[cur ^ 1];
        {   // nt = 0
            float ef = fminf(fmaf(zf0, NEG_LOG2E, p[0]), 80.0f);
            float ei = fminf(fmaf(zi0, NEG_LOG2E, p[2]), 80.0f);
            float A1 = 1.0f + __builtin_amdgcn_exp2f(ef);
            float B1 = 1.0f + __builtin_amdgcn_exp2f(ei);
            float N  = fmaf(hm0, B1, p[4] * A1);
            hm0 = N * __builtin_amdgcn_rcpf(A1 * B1);
            hn[row * 272 + cb + colq] = (bf16)hm0;
        }
        {   // nt = 1
            float ef = fminf(fmaf(zf1, NEG_LOG2E, p[1]), 80.0f);
            float ei = fminf(fmaf(zi1, NEG_LOG2E, p[3]), 80.0f);
            float A1 = 1.0f + __builtin_amdgcn_exp2f(ef);
            float B1 = 1.0f + __builtin_amdgcn_exp2f(ei);
            float N  = fmaf(hm1, B1, p[5] * A1);
            hm1 = N * __builtin_amdgcn_rcpf(A1 * B1);
            hn[row * 272 + cb + 16 + colq] = (bf16)hm1;
        }
        // LDS-visibility barrier only; global prefetch stays in flight.
        asm volatile("s_waitcnt lgkmcnt(0)\n\ts_barrier" ::: "memory");
        if (hout) {   // coalesced store of h_t from the just-written buffer
            int r2 = tid >> 7, c2 = (tid & 127) * 2;
            bf16x2 v = *(const bf16x2*)(hn + r2 * 272 + c2);
            *(bf16x2*)(hout + ((size_t)t * 128 + bbase + r2) * 256 + c2) = v;
        }
        cur ^= 1;
    };

    // depth-2 prefetch, 4 statically-named buffers, loop unrolled x4
    float bA[6], bB[6], bC[6], bD[6];
    PLD(bA, 0);
    PLD(bB, 1);
    for (int t = 0; t < T; t += 4) {
        PLD(bC, (t + 2 < T) ? t + 2 : T - 1);
        step(t, bA);
        PLD(bD, (t + 3 < T) ? t + 3 : T - 1);
        step(t + 1, bB);
        PLD(bA, (t + 4 < T) ? t + 4 : T - 1);
        step(t + 2, bC);
        PLD(bB, (t + 5 < T) ? t + 5 : T - 1);
        step(t + 3, bD);
    }
#undef PLD
    hstate[(size_t)(bbase + row) * 256 + cb + colq]      = hm0;
    hstate[(size_t)(bbase + row) * 256 + cb + 16 + colq] = hm1;
}

// ---------------------------------------------------------------------------
// fc head: out[b][o] = fcb[o] + sum_h h2[b][h] * fcWT[h][o]   (all fp32)
// ---------------------------------------------------------------------------
__global__ void fc_head(const float* __restrict__ h2, const float* __restrict__ fcWT,
                        const float* __restrict__ fcb, float* __restrict__ out)
{
    int b = blockIdx.x, o = threadIdx.x;
    __shared__ float hrow[256];
    hrow[o] = h2[(size_t)b * 256 + o];
    __syncthreads();
    float acc = fcb[o];
#pragma unroll 8
    for (int h = 0; h < 256; ++h)
        acc = fmaf(hrow[h], fcWT[h * 256 + o], acc);
    out[(size_t)b * 256 + o] = acc;
}

// ---------------------------------------------------------------------------
extern "C" void kernel_launch(void* const* d_in, const int* in_sizes, int n_in,
                              void* d_out, int out_size, void* d_ws, size_t ws_size,
                              hipStream_t stream)
{
    (void)in_sizes; (void)n_in; (void)out_size;
    const float* x   = (const float*)d_in[0];
    const float* Wf0 = (const float*)d_in[1];
    const float* bf0 = (const float*)d_in[2];
    const float* Uf0 = (const float*)d_in[3];
    const float* Wi0 = (const float*)d_in[4];
    const float* bi0 = (const float*)d_in[5];
    const float* Ui0 = (const float*)d_in[6];
    const float* Wx0 = (const float*)d_in[7];
    const float* bx0 = (const float*)d_in[8];
    const float* Wf1 = (const float*)d_in[9];
    const float* bf1 = (const float*)d_in[10];
    const float* Uf1 = (const float*)d_in[11];
    const float* Wi1 = (const float*)d_in[12];
    const float* bi1 = (const float*)d_in[13];
    const float* Ui1 = (const float*)d_in[14];
    const float* Wx1 = (const float*)d_in[15];
    const float* bx1 = (const float*)d_in[16];
    const float* fcW = (const float*)d_in[17];
    const float* fcb = (const float*)d_in[18];

    char* p = (char*)d_ws;
    auto alloc = [&](size_t bytes) -> char* {
        char* r = p; p += (bytes + 255) & ~(size_t)255; return r;
    };
    bf16*  W0cat = (bf16*)alloc(768 * 256 * 2);
    bf16*  W1cat = (bf16*)alloc(768 * 256 * 2);
    bf16*  U0cat = (bf16*)alloc(512 * 256 * 2);
    bf16*  U1cat = (bf16*)alloc(512 * 256 * 2);
    float* b0cat = (float*)alloc(768 * 4);
    float* b1cat = (float*)alloc(768 * 4);
    float* fcWT  = (float*)alloc(256 * 256 * 4);
    float* h0s   = (float*)alloc(128 * 256 * 4);
    float* h1s   = (float*)alloc(128 * 256 * 4);
    size_t fixed = (size_t)(p - (char*)d_ws);

    // per-chunk bytes = T_c * (128*256*2 + 128*768*4 + 128*256*2 + 128*768*4)
    //                 = T_c * 917504
    int T_c = 2048;
    while (T_c > 32 && fixed + (size_t)T_c * 917504 + 4096 > ws_size) T_c >>= 1;
    bf16*  xa   = (bf16*)alloc((size_t)T_c * 128 * 256 * 2);
    float* pre0 = (float*)alloc((size_t)T_c * 128 * 768 * 4);
    bf16*  h1b  = (bf16*)alloc((size_t)T_c * 128 * 256 * 2);
    float* pre1 = (float*)alloc((size_t)T_c * 128 * 768 * 4);

    hipMemsetAsync(h0s, 0, 128 * 256 * 4, stream);
    hipMemsetAsync(h1s, 0, 128 * 256 * 4, stream);

    prep_weights<<<512, 256, 0, stream>>>(Wf0, Wi0, Wx0, Wf1, Wi1, Wx1,
                                          Uf0, Ui0, Uf1, Ui1,
                                          bf0, bi0, bx0, bf1, bi1, bx1, fcW,
                                          W0cat, W1cat, U0cat, U1cat, b0cat, b1cat, fcWT);

    int NC = S_ / T_c;
    for (int c = 0; c < NC; ++c) {
        int t0 = c * T_c;
        convert_x<<<T_c * 32, 256, 0, stream>>>(x, xa, t0, T_c);
        gemm_preact<<<dim3(T_c, 6), 256, 0, stream>>>(xa, W0cat, b0cat, pre0);
        rec_layer<<<32, 512, 0, stream>>>(pre0, h1b, U0cat, h0s, T_c);
        gemm_preact<<<dim3(T_c, 6), 256, 0, stream>>>(h1b, W1cat, b1cat, pre1);
        rec_layer<<<32, 512, 0, stream>>>(pre1, nullptr, U1cat, h1s, T_c);
    }
    fc_head<<<128, 256, 0, stream>>>(h1s, fcWT, fcb, (float*)d_out);
}

// Round 4
// 2306.318 us; speedup vs baseline: 2.3505x; 1.8271x over previous
//
#include <hip/hip_runtime.h>
#include <hip/hip_bf16.h>
#include <cstdint>
#include <cstddef>

// ---------------------------------------------------------------------------
// RANNet: 2-layer recurrent additive network, B=128 S=2048 D=H=256, fc head.
// Round 6: software-pipeline the whole network across chunks in ONE fused
// "mega" launch per pipeline tick:
//     mega(k) = rec0(chunk k) || gemm1(chunk k-1) || rec1(chunk k-2)
//               || gemm0(chunk k+1)
// All four stages are data-independent within a tick; every dependency spans
// exactly one launch boundary (stream-ordered). 2-deep ping-pong on pre0/
// pre1/h1b. T_c=128, NC=16: rec critical path = (NC+2)*T_c = 2304 steps
// (vs 4096 serial), and all GEMM time hides under rec.
// An 84 KB LDS pad per block forces 1 block/CU so gemm blocks can never
// co-reside with a rec block and steal its MFMA issue slots.
// rec internals unchanged from round 5 (at its per-CU MFMA issue floor).
// ---------------------------------------------------------------------------

typedef __bf16 bf16;
typedef __bf16 bf16x8 __attribute__((ext_vector_type(8)));
typedef __bf16 bf16x4 __attribute__((ext_vector_type(4)));
typedef __bf16 bf16x2 __attribute__((ext_vector_type(2)));
typedef float  floatx4 __attribute__((ext_vector_type(4)));

#define B_   128
#define S_   2048
#define H_   256
#define NEG_LOG2E -1.442695040888963f
#define NGB  160                 // gemm worker blocks in mega
#define SMEM_BYTES (84 * 1024)   // > 160KiB/2 -> guarantees 1 block per CU

// ---------------------------------------------------------------------------
// Weight prep: concat + fp32->bf16 ( W*cat rows = [Wf;Wi;Wx], U*cat = [Uf;Ui] )
// fcWT = transpose(fcW) kept fp32 for the epilogue.
// ---------------------------------------------------------------------------
__global__ void prep_weights(
    const float* __restrict__ Wf0, const float* __restrict__ Wi0, const float* __restrict__ Wx0,
    const float* __restrict__ Wf1, const float* __restrict__ Wi1, const float* __restrict__ Wx1,
    const float* __restrict__ Uf0, const float* __restrict__ Ui0,
    const float* __restrict__ Uf1, const float* __restrict__ Ui1,
    const float* __restrict__ bf0, const float* __restrict__ bi0, const float* __restrict__ bx0,
    const float* __restrict__ bf1, const float* __restrict__ bi1, const float* __restrict__ bx1,
    const float* __restrict__ fcW,
    bf16* __restrict__ W0cat, bf16* __restrict__ W1cat,
    bf16* __restrict__ U0cat, bf16* __restrict__ U1cat,
    float* __restrict__ b0cat, float* __restrict__ b1cat, float* __restrict__ fcWT)
{
    int tid = blockIdx.x * blockDim.x + threadIdx.x;
    int nth = gridDim.x * blockDim.x;
    for (int idx = tid; idx < 768 * 256; idx += nth) {
        int r = idx >> 8, k = idx & 255, rr = r & 255;
        const float* s0 = (r < 256) ? Wf0 : ((r < 512) ? Wi0 : Wx0);
        const float* s1 = (r < 256) ? Wf1 : ((r < 512) ? Wi1 : Wx1);
        W0cat[idx] = (bf16)s0[rr * 256 + k];
        W1cat[idx] = (bf16)s1[rr * 256 + k];
    }
    for (int idx = tid; idx < 512 * 256; idx += nth) {
        int r = idx >> 8, k = idx & 255, rr = r & 255;
        U0cat[idx] = (bf16)((r < 256 ? Uf0 : Ui0)[rr * 256 + k]);
        U1cat[idx] = (bf16)((r < 256 ? Uf1 : Ui1)[rr * 256 + k]);
    }
    for (int idx = tid; idx < 768; idx += nth) {
        const float* s0 = (idx < 256) ? bf0 : ((idx < 512) ? bi0 : bx0);
        const float* s1 = (idx < 256) ? bf1 : ((idx < 512) ? bi1 : bx1);
        b0cat[idx] = s0[idx & 255];
        b1cat[idx] = s1[idx & 255];
    }
    for (int idx = tid; idx < 256 * 256; idx += nth) {
        int h = idx >> 8, o = idx & 255;
        fcWT[idx] = fcW[o * 256 + h];   // fcWT[h][o]
    }
}

// ---------------------------------------------------------------------------
// x (fp32, [B][S][D]) -> xa (bf16, [S][B][D])  (full sequence, one launch)
// ---------------------------------------------------------------------------
__global__ void convert_x(const float* __restrict__ x, bf16* __restrict__ xa, int t0, int T)
{
    int tid = blockIdx.x * blockDim.x + threadIdx.x;   // T*128*64 threads
    int d4 = tid & 63;
    int b  = (tid >> 6) & 127;
    int t  = tid >> 13;
    if (t >= T) return;
    const float4* src = (const float4*)(x + ((size_t)b * S_ + t0 + t) * H_) + d4;
    float4 v = *src;
    bf16x4 o = { (bf16)v.x, (bf16)v.y, (bf16)v.z, (bf16)v.w };
    *((bf16x4*)(xa + ((size_t)t * B_ + b) * H_) + d4) = o;
}

// ---------------------------------------------------------------------------
// Device: one 128x128 preact GEMM tile (512 thr, 8 waves, 64x32 per wave).
// C[128 rows][128 of 768 cols] = A[128][256] @ W[768][256]^T + bias, written
// f32 into rec layout preP[(t*32 + (m>>2))*3072 + c*4 + (m&3)];
// f/i (c<512) pre-scaled by -log2(e). Stores are coalesced float4.
// ---------------------------------------------------------------------------
__device__ __forceinline__ void gemm_tile(
    char* smem,
    const bf16* __restrict__ Abase,   // 128 rows, row stride 256
    const bf16* __restrict__ W, const float* __restrict__ bias,
    float* __restrict__ preP, int t, int nb)
{
    bf16* At = (bf16*)smem;           // [128][32]
    bf16* Bt = (bf16*)smem + 128 * 32;
    int n0 = nb * 128;
    int tid = threadIdx.x;
    int lane = tid & 63, wave = tid >> 6;
    int wm = (wave >> 2) * 64, wn = (wave & 3) * 32;
    int qm = lane & 15, qk = lane >> 4;
    floatx4 acc[4][2] = {};

    for (int k0 = 0; k0 < 256; k0 += 32) {
        {   // stage: 512 threads x one 16B chunk per buffer
            int c = tid, row = c >> 2, kc = c & 3;
            *(bf16x8*)(At + c * 8) = *(const bf16x8*)(Abase + (size_t)row * 256 + k0 + kc * 8);
            *(bf16x8*)(Bt + c * 8) = *(const bf16x8*)(W + (size_t)(n0 + row) * 256 + k0 + kc * 8);
        }
        __syncthreads();
        bf16x8 af[4], bfr[2];
#pragma unroll
        for (int i = 0; i < 4; ++i)
            af[i] = *(const bf16x8*)(At + (wm + i * 16 + qm) * 32 + qk * 8);
#pragma unroll
        for (int n = 0; n < 2; ++n)
            bfr[n] = *(const bf16x8*)(Bt + (wn + n * 16 + qm) * 32 + qk * 8);
#pragma unroll
        for (int mi = 0; mi < 4; ++mi)
#pragma unroll
            for (int ni = 0; ni < 2; ++ni)
                acc[mi][ni] = __builtin_amdgcn_mfma_f32_16x16x32_bf16(af[mi], bfr[ni], acc[mi][ni], 0, 0, 0);
        __syncthreads();
    }
#pragma unroll
    for (int mi = 0; mi < 4; ++mi) {
        int b = wm + mi * 16 + qk * 4;        // + r ; multiple of 4
        int wgi = b >> 2;
#pragma unroll
        for (int ni = 0; ni < 2; ++ni) {
            int c = n0 + wn + ni * 16 + qm;
            int g = c >> 8;
            float bb = bias[c];
            float4 v;
            float* vp = (float*)&v;
#pragma unroll
            for (int r = 0; r < 4; ++r) {
                float val = acc[mi][ni][r] + bb;
                vp[r] = (g < 2) ? NEG_LOG2E * val : val;
            }
            *(float4*)(preP + ((size_t)t * 32 + wgi) * 3072 + (size_t)c * 4) = v;
        }
    }
}

// ---------------------------------------------------------------------------
// Device: recurrence for one WG (4 batch rows), unchanged from round 5.
// ---------------------------------------------------------------------------
__device__ __forceinline__ void rec_wg(
    char* smem, int wg,
    const float* __restrict__ preP,  // [T][32 wg][768 c][4 r] f32
    bf16* __restrict__ hout,         // [T][128][256] bf16, or nullptr
    const bf16* __restrict__ Ucat,   // [512][256] = [Uf;Ui]
    float* __restrict__ hstate,      // [128][256] in/out
    int T)
{
    bf16* hbb = (bf16*)smem;             // [2][4*272], 544B row stride
    const int tid = threadIdx.x, lane = tid & 63, wave = tid >> 6;
    const int qm = lane & 15, qk = lane >> 4;
    const int row = qk;                  // 0..3 = output row this lane owns
    const int colq = qm;                 // 0..15
    const int bbase = wg * 4, cb = wave * 32;
    const bool selhi16 = (lane & 16) != 0;   // reg-select masks (hoisted)
    const bool selhi32 = (lane & 32) != 0;

    // stationary U fragments (B-operand layout): row n = col index, k contig
    bf16x8 Ufr[2][8], Uir[2][8];
#pragma unroll
    for (int nt = 0; nt < 2; ++nt)
#pragma unroll
        for (int kt = 0; kt < 8; ++kt) {
            Ufr[nt][kt] = *(const bf16x8*)(Ucat + (size_t)(cb + nt * 16 + qm) * 256 + kt * 32 + qk * 8);
            Uir[nt][kt] = *(const bf16x8*)(Ucat + (size_t)(256 + cb + nt * 16 + qm) * 256 + kt * 32 + qk * 8);
        }
    {   // init LDS h (buf 0) from fp32 state: 4 rows x 256 cols, 2 cols/thread
        int r2 = tid >> 7, c2 = (tid & 127) * 2;
        const float* hs = hstate + (size_t)(bbase + r2) * 256 + c2;
        bf16x2 v = { (bf16)hs[0], (bf16)hs[1] };
        *(bf16x2*)(hbb + r2 * 272 + c2) = v;
    }
    float hm0 = hstate[(size_t)(bbase + row) * 256 + cb + colq];
    float hm1 = hstate[(size_t)(bbase + row) * 256 + cb + 16 + colq];
    __syncthreads();

    // per-lane preact base: idx = t*98304 + wg*3072 + (g*256+cb+nt*16+colq)*4 + row
    const float* pw = preP + (size_t)wg * 3072 + (size_t)((cb + colq) * 4 + row);
#define PLD(dst, tt) { size_t o_ = (size_t)(tt) * 98304;                          \
        dst[0] = pw[o_];        dst[1] = pw[o_ + 64];   dst[2] = pw[o_ + 1024];   \
        dst[3] = pw[o_ + 1088]; dst[4] = pw[o_ + 2048]; dst[5] = pw[o_ + 2112]; }

    int cur = 0;

    // every lane: reg j = z[row=j][col=lane&15]  ->  pick reg (lane>>4)
    auto spread = [&](floatx4 v) -> float {
        float s01 = selhi16 ? v[1] : v[0];
        float s23 = selhi16 ? v[3] : v[2];
        return selhi32 ? s23 : s01;
    };

    auto step = [&](int t, const float* p) {
        floatx4 f0{}, f1{}, i0{}, i1{};
        const bf16* hc = hbb + cur * (4 * 272);
#pragma unroll
        for (int kt = 0; kt < 8; ++kt) {
            bf16x8 a = *(const bf16x8*)(hc + (qm & 3) * 272 + kt * 32 + qk * 8);
            f0 = __builtin_amdgcn_mfma_f32_16x16x32_bf16(a, Ufr[0][kt], f0, 0, 0, 0);
            f1 = __builtin_amdgcn_mfma_f32_16x16x32_bf16(a, Ufr[1][kt], f1, 0, 0, 0);
            i0 = __builtin_amdgcn_mfma_f32_16x16x32_bf16(a, Uir[0][kt], i0, 0, 0, 0);
            i1 = __builtin_amdgcn_mfma_f32_16x16x32_bf16(a, Uir[1][kt], i1, 0, 0, 0);
        }
        float zf0 = spread(f0), zf1 = spread(f1);
        float zi0 = spread(i0), zi1 = spread(i1);
        bf16* hn = hbb + (cur ^ 1) * (4 * 272);
        {   // nt = 0
            float ef = fminf(fmaf(zf0, NEG_LOG2E, p[0]), 80.0f);
            float ei = fminf(fmaf(zi0, NEG_LOG2E, p[2]), 80.0f);
            float A1 = 1.0f + __builtin_amdgcn_exp2f(ef);
            float B1 = 1.0f + __builtin_amdgcn_exp2f(ei);
            float N  = fmaf(hm0, B1, p[4] * A1);
            hm0 = N * __builtin_amdgcn_rcpf(A1 * B1);
            hn[row * 272 + cb + colq] = (bf16)hm0;
        }
        {   // nt = 1
            float ef = fminf(fmaf(zf1, NEG_LOG2E, p[1]), 80.0f);
            float ei = fminf(fmaf(zi1, NEG_LOG2E, p[3]), 80.0f);
            float A1 = 1.0f + __builtin_amdgcn_exp2f(ef);
            float B1 = 1.0f + __builtin_amdgcn_exp2f(ei);
            float N  = fmaf(hm1, B1, p[5] * A1);
            hm1 = N * __builtin_amdgcn_rcpf(A1 * B1);
            hn[row * 272 + cb + 16 + colq] = (bf16)hm1;
        }
        // LDS-visibility barrier only; global prefetch stays in flight.
        asm volatile("s_waitcnt lgkmcnt(0)\n\ts_barrier" ::: "memory");
        if (hout) {   // coalesced store of h_t from the just-written buffer
            int r2 = tid >> 7, c2 = (tid & 127) * 2;
            bf16x2 v = *(const bf16x2*)(hn + r2 * 272 + c2);
            *(bf16x2*)(hout + ((size_t)t * 128 + bbase + r2) * 256 + c2) = v;
        }
        cur ^= 1;
    };

    // depth-2 prefetch, 4 statically-named buffers, loop unrolled x4
    float bA[6], bB[6], bC[6], bD[6];
    PLD(bA, 0);
    PLD(bB, 1);
    for (int t = 0; t < T; t += 4) {
        PLD(bC, (t + 2 < T) ? t + 2 : T - 1);
        step(t, bA);
        PLD(bD, (t + 3 < T) ? t + 3 : T - 1);
        step(t + 1, bB);
        PLD(bA, (t + 4 < T) ? t + 4 : T - 1);
        step(t + 2, bC);
        PLD(bB, (t + 5 < T) ? t + 5 : T - 1);
        step(t + 3, bD);
    }
#undef PLD
    hstate[(size_t)(bbase + row) * 256 + cb + colq]      = hm0;
    hstate[(size_t)(bbase + row) * 256 + cb + 16 + colq] = hm1;
}

// ---------------------------------------------------------------------------
// Mega pipeline tick: blocks 0-31 rec0(chunk k), 32-63 rec1(chunk k-2),
// 64..64+NGB-1 grid-stride over gemm0(chunk k+1) + gemm1(chunk k-1) tiles.
// flags: bit0 rec0, bit1 gemm1, bit2 rec1, bit3 gemm0.
// ---------------------------------------------------------------------------
__global__ __launch_bounds__(512) void mega(
    const bf16* __restrict__ xa, int t0n,
    const bf16* __restrict__ W0, const float* __restrict__ b0,
    const bf16* __restrict__ W1, const float* __restrict__ b1,
    const bf16* __restrict__ U0, const bf16* __restrict__ U1,
    float* __restrict__ h0s, float* __restrict__ h1s,
    float* __restrict__ pre0n,        // gemm0 out  (chunk k+1)
    const float* __restrict__ pre0c,  // rec0  in   (chunk k)
    bf16*  __restrict__ h1bc,         // rec0  out  (chunk k)
    const bf16* __restrict__ h1bp,    // gemm1 in   (chunk k-1)
    float* __restrict__ pre1p,        // gemm1 out  (chunk k-1)
    const float* __restrict__ pre1pp, // rec1  in   (chunk k-2)
    int flags, int T)
{
    __shared__ __align__(16) char smem[SMEM_BYTES];
    int bx = blockIdx.x;
    if (bx < 32) {
        if (flags & 1) rec_wg(smem, bx, pre0c, h1bc, U0, h0s, T);
        return;
    }
    if (bx < 64) {
        if (flags & 4) rec_wg(smem, bx - 32, pre1pp, nullptr, U1, h1s, T);
        return;
    }
    int ng0 = (flags & 8) ? T * 6 : 0;
    int ng1 = (flags & 2) ? T * 6 : 0;
    for (int tile = bx - 64; tile < ng0 + ng1; tile += NGB) {
        bool is0 = tile < ng0;
        int tt = is0 ? tile : tile - ng0;
        int t = tt / 6, nb = tt - t * 6;
        const bf16* A = is0 ? (xa + (size_t)(t0n + t) * 32768)
                            : (h1bp + (size_t)t * 32768);
        gemm_tile(smem, A, is0 ? W0 : W1, is0 ? b0 : b1,
                  is0 ? pre0n : pre1p, t, nb);
    }
}

// ---------------------------------------------------------------------------
// fc head: out[b][o] = fcb[o] + sum_h h2[b][h] * fcWT[h][o]   (all fp32)
// ---------------------------------------------------------------------------
__global__ void fc_head(const float* __restrict__ h2, const float* __restrict__ fcWT,
                        const float* __restrict__ fcb, float* __restrict__ out)
{
    int b = blockIdx.x, o = threadIdx.x;
    __shared__ float hrow[256];
    hrow[o] = h2[(size_t)b * 256 + o];
    __syncthreads();
    float acc = fcb[o];
#pragma unroll 8
    for (int h = 0; h < 256; ++h)
        acc = fmaf(hrow[h], fcWT[h * 256 + o], acc);
    out[(size_t)b * 256 + o] = acc;
}

// ---------------------------------------------------------------------------
extern "C" void kernel_launch(void* const* d_in, const int* in_sizes, int n_in,
                              void* d_out, int out_size, void* d_ws, size_t ws_size,
                              hipStream_t stream)
{
    (void)in_sizes; (void)n_in; (void)out_size;
    const float* x   = (const float*)d_in[0];
    const float* Wf0 = (const float*)d_in[1];
    const float* bf0 = (const float*)d_in[2];
    const float* Uf0 = (const float*)d_in[3];
    const float* Wi0 = (const float*)d_in[4];
    const float* bi0 = (const float*)d_in[5];
    const float* Ui0 = (const float*)d_in[6];
    const float* Wx0 = (const float*)d_in[7];
    const float* bx0 = (const float*)d_in[8];
    const float* Wf1 = (const float*)d_in[9];
    const float* bf1 = (const float*)d_in[10];
    const float* Uf1 = (const float*)d_in[11];
    const float* Wi1 = (const float*)d_in[12];
    const float* bi1 = (const float*)d_in[13];
    const float* Ui1 = (const float*)d_in[14];
    const float* Wx1 = (const float*)d_in[15];
    const float* bx1 = (const float*)d_in[16];
    const float* fcW = (const float*)d_in[17];
    const float* fcb = (const float*)d_in[18];

    char* p = (char*)d_ws;
    auto alloc = [&](size_t bytes) -> char* {
        char* r = p; p += (bytes + 255) & ~(size_t)255; return r;
    };
    bf16*  W0cat = (bf16*)alloc(768 * 256 * 2);
    bf16*  W1cat = (bf16*)alloc(768 * 256 * 2);
    bf16*  U0cat = (bf16*)alloc(512 * 256 * 2);
    bf16*  U1cat = (bf16*)alloc(512 * 256 * 2);
    float* b0cat = (float*)alloc(768 * 4);
    float* b1cat = (float*)alloc(768 * 4);
    float* fcWT  = (float*)alloc(256 * 256 * 4);
    float* h0s   = (float*)alloc(128 * 256 * 4);
    float* h1s   = (float*)alloc(128 * 256 * 4);
    size_t fixed = (size_t)(p - (char*)d_ws);

    // need(T_c) = fixed + xa(full S) + 2*pre0 + 2*pre1 + 2*h1b
    //           = fixed + 134.2MB + T_c * (4*393216 + 2*65536)
    int T_c = 128;
    while (T_c > 32 &&
           fixed + 134217728ULL + (size_t)T_c * 1703936ULL + 4096 > ws_size)
        T_c >>= 1;
    bf16*  xa    = (bf16*)alloc((size_t)S_ * 128 * 256 * 2);
    float* pre0s[2], *pre1s[2];
    bf16*  h1bs[2];
    pre0s[0] = (float*)alloc((size_t)T_c * 128 * 768 * 4);
    pre0s[1] = (float*)alloc((size_t)T_c * 128 * 768 * 4);
    pre1s[0] = (float*)alloc((size_t)T_c * 128 * 768 * 4);
    pre1s[1] = (float*)alloc((size_t)T_c * 128 * 768 * 4);
    h1bs[0]  = (bf16*)alloc((size_t)T_c * 128 * 256 * 2);
    h1bs[1]  = (bf16*)alloc((size_t)T_c * 128 * 256 * 2);

    hipMemsetAsync(h0s, 0, 128 * 256 * 4, stream);
    hipMemsetAsync(h1s, 0, 128 * 256 * 4, stream);

    prep_weights<<<512, 256, 0, stream>>>(Wf0, Wi0, Wx0, Wf1, Wi1, Wx1,
                                          Uf0, Ui0, Uf1, Ui1,
                                          bf0, bi0, bx0, bf1, bi1, bx1, fcW,
                                          W0cat, W1cat, U0cat, U1cat, b0cat, b1cat, fcWT);
    convert_x<<<S_ * 32, 256, 0, stream>>>(x, xa, 0, S_);

    int NC = S_ / T_c;
    for (int k = -1; k <= NC + 1; ++k) {
        int flags = 0;
        if (k >= 0 && k < NC)     flags |= 1;   // rec0 chunk k
        if (k >= 1 && k <= NC)    flags |= 2;   // gemm1 chunk k-1
        if (k >= 2 && k <= NC+1)  flags |= 4;   // rec1 chunk k-2
        if (k <= NC - 2)          flags |= 8;   // gemm0 chunk k+1
        mega<<<64 + NGB, 512, 0, stream>>>(
            xa, (k + 1) * T_c,
            W0cat, b0cat, W1cat, b1cat, U0cat, U1cat, h0s, h1s,
            pre0s[(k + 1) & 1],   // gemm0 out
            pre0s[k & 1],         // rec0 in
            h1bs[k & 1],          // rec0 out
            h1bs[(k - 1) & 1],    // gemm1 in
            pre1s[(k - 1) & 1],   // gemm1 out
            pre1s[k & 1],         // rec1 in  ((k-2)&1 == k&1)
            flags, T_c);
    }
    fc_head<<<128, 256, 0, stream>>>(h1s, fcWT, fcb, (float*)d_out);
}